// Round 8
// baseline (79.003 us; speedup 1.0000x reference)
//
#include <hip/hip_runtime.h>
#include <math.h>

#define VOCAB 100000
#define BATCH 4096
#define DOC_LEN 200
#define EMBED_DIM 300
#define NUM_CLASSES 20

// ---------------------------------------------------------------------------
// Kernel 1:  P[v][c] = sum_k emb[v][k] * (W[c][k]/DOC_LEN)
// K-split x R=2: 5 waves = 5 disjoint 60-dim K-slices; each lane owns rows
// r and r+64 so every W-quad broadcast feeds 8 FMAs (4 classes x 2 rows).
//   - chip ds_read_b128 count halves vs r7 (1.17M vs 2.34M): the r7
//     post-mortem showed the per-CU LDS pipe (~46 us) was the wall.
//   - NO cross-chunk load pipeline: that was r5's spiller (+48 live regs ->
//     128-VGPR cliff). Single-generation chunk loads = 24 staging regs;
//     live ~= 80 (40 acc + 24 stage + quad + addr). Latency hidden by
//     15 waves/CU x 6 independent loads per chunk.
//   - partials in LDS [s][c][r] (r contiguous): conflict-free writes AND
//     reads (r7's [s][r][20] writes cost 856K conflict cycles).
//   - only compile-time register indexing (r6), no launch-bounds min (r2),
//     W in LDS not scalar path (r3).
// ---------------------------------------------------------------------------
#define K1_BLOCK 320
#define K1_RPB   128                                   // rows per block
#define K1_GRID  ((VOCAB + K1_RPB - 1) / K1_RPB)       // 782

// one k-value: 5 uniform W-quad reads, 8 FMAs each (4 classes x 2 rows)
#define FMA2_K(av, bv, kw)                                                \
    {                                                                     \
        _Pragma("unroll")                                                 \
        for (int c4 = 0; c4 < NUM_CLASSES; c4 += 4) {                     \
            const float4 w =                                              \
                *reinterpret_cast<const float4*>(&sWT[(kw)][c4]);         \
            acc0[c4 + 0] += (av) * w.x;  acc1[c4 + 0] += (bv) * w.x;      \
            acc0[c4 + 1] += (av) * w.y;  acc1[c4 + 1] += (bv) * w.y;      \
            acc0[c4 + 2] += (av) * w.z;  acc1[c4 + 2] += (bv) * w.z;      \
            acc0[c4 + 3] += (av) * w.w;  acc1[c4 + 3] += (bv) * w.w;      \
        }                                                                 \
    }

__global__ __launch_bounds__(K1_BLOCK) void project_kernel(
    const float* __restrict__ emb,   // (VOCAB, 300)
    const float* __restrict__ W,     // (20, 300)
    float*       __restrict__ P)     // (VOCAB, 20)  [workspace]
{
    // union: sWT [300][20] (24 KB) during compute; partials [5][20][128]
    // (51.2 KB) afterwards  ->  3 blocks/CU (160/51.2), 15 waves/CU.
    __shared__ float smem[5 * NUM_CLASSES * K1_RPB];   // 12800 floats
    float (*sWT)[NUM_CLASSES] = reinterpret_cast<float (*)[NUM_CLASSES]>(smem);

    const float inv = 1.0f / (float)DOC_LEN;
    for (int i = threadIdx.x; i < NUM_CLASSES * EMBED_DIM; i += K1_BLOCK) {
        const int c = i / EMBED_DIM;
        const int k = i - c * EMBED_DIM;
        sWT[k][c] = W[i] * inv;                        // fold mean into W
    }
    __syncthreads();

    const int s     = threadIdx.x >> 6;                // k-slice = wave, 0..4
    const int lane  = threadIdx.x & 63;
    const int rbase = blockIdx.x * K1_RPB;
    const int r0 = rbase + lane;
    const int r1 = r0 + 64;
    const float* __restrict__ e0 =
        emb + (size_t)(r0 < VOCAB ? r0 : VOCAB - 1) * EMBED_DIM + s * 60;
    const float* __restrict__ e1 =
        emb + (size_t)(r1 < VOCAB ? r1 : VOCAB - 1) * EMBED_DIM + s * 60;

    float acc0[NUM_CLASSES], acc1[NUM_CLASSES];
    #pragma unroll
    for (int c = 0; c < NUM_CLASSES; ++c) { acc0[c] = 0.0f; acc1[c] = 0.0f; }

    // 60-dim slice = 5 chunks of 12 floats; 6 independent loads per chunk.
    #pragma unroll
    for (int kk = 0; kk < 5; ++kk) {
        const int k = 12 * kk;
        const float4 a0 = *reinterpret_cast<const float4*>(e0 + k);
        const float4 a1 = *reinterpret_cast<const float4*>(e0 + k + 4);
        const float4 a2 = *reinterpret_cast<const float4*>(e0 + k + 8);
        const float4 b0 = *reinterpret_cast<const float4*>(e1 + k);
        const float4 b1 = *reinterpret_cast<const float4*>(e1 + k + 4);
        const float4 b2 = *reinterpret_cast<const float4*>(e1 + k + 8);

        const int kb = s * 60 + k;                     // W row for this chunk
        FMA2_K(a0.x, b0.x, kb + 0)  FMA2_K(a0.y, b0.y, kb + 1)
        FMA2_K(a0.z, b0.z, kb + 2)  FMA2_K(a0.w, b0.w, kb + 3)
        FMA2_K(a1.x, b1.x, kb + 4)  FMA2_K(a1.y, b1.y, kb + 5)
        FMA2_K(a1.z, b1.z, kb + 6)  FMA2_K(a1.w, b1.w, kb + 7)
        FMA2_K(a2.x, b2.x, kb + 8)  FMA2_K(a2.y, b2.y, kb + 9)
        FMA2_K(a2.z, b2.z, kb + 10) FMA2_K(a2.w, b2.w, kb + 11)
    }
    __syncthreads();                                   // done reading sWT

    // partials [s][c][r]: consecutive lanes -> consecutive floats (no
    // conflicts); 20 b32 writes per thread.
    float* sP = smem;
    #pragma unroll
    for (int c = 0; c < NUM_CLASSES; ++c) {
        sP[(s * NUM_CLASSES + c) * K1_RPB + lane]      = acc0[c];
        sP[(s * NUM_CLASSES + c) * K1_RPB + lane + 64] = acc1[c];
    }
    __syncthreads();

    // reduce 5 slices: 2560 outputs, 8/thread; oi enumerated c-major so
    // consecutive threads read consecutive r (stride-1, conflict-free).
    #pragma unroll
    for (int j = 0; j < 8; ++j) {
        const int oi = threadIdx.x + j * K1_BLOCK;     // 0..2559
        const int r  = oi & (K1_RPB - 1);              // oi % 128
        const int c  = oi >> 7;                        // oi / 128
        float v = sP[(0 * NUM_CLASSES + c) * K1_RPB + r]
                + sP[(1 * NUM_CLASSES + c) * K1_RPB + r]
                + sP[(2 * NUM_CLASSES + c) * K1_RPB + r]
                + sP[(3 * NUM_CLASSES + c) * K1_RPB + r]
                + sP[(4 * NUM_CLASSES + c) * K1_RPB + r];
        const int gr = rbase + r;
        if (gr < VOCAB)
            P[(size_t)gr * NUM_CLASSES + c] = v;
    }
}

// ---------------------------------------------------------------------------
// Kernel 2: out[doc] = softmax( sum_l P[x[doc][l]] + b )   (unchanged)
// One wave per doc; 64 lanes = 3 position-groups x 20 classes.
// ---------------------------------------------------------------------------
#define K2_BLOCK 256
#define DOCS_PER_BLOCK 4

__global__ __launch_bounds__(K2_BLOCK) void pool_softmax_kernel(
    const float* __restrict__ P,     // (VOCAB, 20), pre-scaled by 1/DOC_LEN
    const float* __restrict__ bias,  // (20,)
    const int*   __restrict__ x,     // (BATCH, 200)
    float*       __restrict__ out)   // (BATCH, 20)
{
    __shared__ int sidx[DOCS_PER_BLOCK][DOC_LEN];

    const int doc0 = blockIdx.x * DOCS_PER_BLOCK;
    const int tid  = threadIdx.x;

    for (int i = tid; i < DOCS_PER_BLOCK * DOC_LEN; i += K2_BLOCK)
        (&sidx[0][0])[i] = x[doc0 * DOC_LEN + i];
    __syncthreads();

    const int wave = tid >> 6;
    const int lane = tid & 63;
    const int doc  = doc0 + wave;
    const int g    = lane / NUM_CLASSES;          // 0..2 active, 3 idle
    const int c    = lane - g * NUM_CLASSES;

    float acc = 0.0f;
    if (g < 3) {
        #pragma unroll 4
        for (int l = g; l < DOC_LEN; l += 3) {
            const int row = sidx[wave][l];        // LDS broadcast per group
            acc += P[(size_t)row * NUM_CLASSES + c];
        }
    }

    const float a1 = __shfl(acc, lane + 20, 64);
    const float a2 = __shfl(acc, lane + 40, 64);

    float v = (lane < NUM_CLASSES) ? (acc + a1 + a2 + bias[c]) : -INFINITY;

    float m = v;
    #pragma unroll
    for (int off = 16; off > 0; off >>= 1)
        m = fmaxf(m, __shfl_xor(m, off, 32));
    const float e = (lane < NUM_CLASSES) ? expf(v - m) : 0.0f;
    float s = e;
    #pragma unroll
    for (int off = 16; off > 0; off >>= 1)
        s += __shfl_xor(s, off, 32);

    if (lane < NUM_CLASSES)
        out[doc * NUM_CLASSES + lane] = e / s;
}

extern "C" void kernel_launch(void* const* d_in, const int* in_sizes, int n_in,
                              void* d_out, int out_size, void* d_ws, size_t ws_size,
                              hipStream_t stream) {
    const float* emb  = (const float*)d_in[0];
    const float* W    = (const float*)d_in[1];
    const float* bias = (const float*)d_in[2];
    const int*   x    = (const int*)d_in[3];
    float* out = (float*)d_out;
    float* P   = (float*)d_ws;   // needs VOCAB*20*4 = 8,000,000 B

    project_kernel<<<K1_GRID, K1_BLOCK, 0, stream>>>(emb, W, P);
    pool_softmax_kernel<<<BATCH / DOCS_PER_BLOCK, K2_BLOCK, 0, stream>>>(P, bias, x, out);
}